// Round 7
// baseline (1179.052 us; speedup 1.0000x reference)
//
#include <hip/hip_runtime.h>
#include <math.h>

typedef __attribute__((ext_vector_type(8)))  short short8;
typedef __attribute__((ext_vector_type(4)))  float float4v;
typedef __attribute__((ext_vector_type(16))) float f32x16;

__device__ __forceinline__ unsigned short f2bf(float f) {
    union { float f; unsigned u; } x; x.f = f;
    unsigned r = x.u + 0x7FFFu + ((x.u >> 16) & 1u);
    return (unsigned short)(r >> 16);
}
__device__ __forceinline__ float bf2f(unsigned short u) {
    union { unsigned u; float f; } x; x.u = ((unsigned)u) << 16;
    return x.f;
}

#define HWSZ ((size_t)512 * 512)

// ---------------- input prep: NCHW f32 (Cin=6) -> NHWC8 bf16 hi + lo planes ----------------
__global__ __launch_bounds__(256)
void prep7_k(const float* __restrict__ in, unsigned short* __restrict__ hi,
             unsigned short* __restrict__ lo)
{
    const int idx = blockIdx.x * 256 + threadIdx.x;   // < 2*512*512
    const int b = idx >> 18, rem = idx & 262143;
    const int h = rem >> 9, w = rem & 511;
    unsigned short vh[8], vl[8];
#pragma unroll
    for (int c = 0; c < 8; ++c) {
        float x = (c < 6) ? in[((size_t)(b * 6 + c)) * HWSZ + (h << 9) + w] : 0.f;
        unsigned short h16 = f2bf(x);
        vh[c] = h16;
        vl[c] = f2bf(x - bf2f(h16));
    }
    const size_t o = ((size_t)idx) * 8;
    *(uint4*)(hi + o) = *(uint4*)vh;
    *(uint4*)(lo + o) = *(uint4*)vl;
}

// ---------------- conv7 weight repack: (64,6,7,7) f32 -> fragment-linear bf16 hi/lo ----------------
__global__ __launch_bounds__(256)
void repack7_k(const float* __restrict__ wsrc, unsigned short* __restrict__ dhi,
               unsigned short* __restrict__ dlo)
{
    const int t = blockIdx.x * 256 + threadIdx.x;   // < 26624
    if (t >= 26624) return;
    const int j = t & 7, l = (t >> 3) & 63, ct = (t >> 9) & 3, kk = t >> 11;
    const int co = ct * 16 + (l & 15);
    const int s = kk * 4 + (l >> 4);
    float v = 0.f;
    if (s < 49 && j < 6)
        v = wsrc[((size_t)(co * 6 + j) * 7 + s / 7) * 7 + s % 7];
    unsigned short h16 = f2bf(v);
    dhi[t] = h16;
    dlo[t] = f2bf(v - bf2f(h16));
}

// ---------------- conv 7x7 MFMA implicit GEMM, split precision, + ReLU ----------------
// out: split-plane NHWC32 bf16  [b][2][512][512][32]
__global__ __launch_bounds__(256)
void conv7_mfma(const unsigned short* __restrict__ inhi,
                const unsigned short* __restrict__ inlo,
                const unsigned short* __restrict__ whi,
                const unsigned short* __restrict__ wlo,
                unsigned short* __restrict__ out)
{
    extern __shared__ char p_lds[];   // [2 planes][8 rows][134 cols][16B]

    const int id = blockIdx.x;                      // 2048 blocks
    const int lid = (id & 7) * 256 + (id >> 3);     // XCD chunk swizzle
    const int w0 = (lid & 3) * 128;
    const int rest = lid >> 2;
    const int h0 = (rest & 255) * 2;
    const int b  = rest >> 8;

    const int tid = threadIdx.x;
    const int wv = tid >> 6, l = tid & 63, lq = l >> 4, lr = l & 15;

    for (int idx = tid; idx < 2144; idx += 256) {   // 2*8*134
        const int plane = idx >= 1072;
        const int rc = plane ? idx - 1072 : idx;
        const int r = rc / 134, c = rc % 134;
        const int hh = h0 - 3 + r, wc = w0 - 3 + c;
        int4 v = make_int4(0, 0, 0, 0);
        if (hh >= 0 && hh < 512 && wc >= 0 && wc < 512) {
            const unsigned short* src = plane ? inlo : inhi;
            v = *(const int4*)(src + ((((size_t)b * 512 + hh) * 512) + wc) * 8);
        }
        *(int4*)(p_lds + (size_t)idx * 16) = v;
    }
    __syncthreads();

    float4v acc[2][2][4];
#pragma unroll
    for (int pr = 0; pr < 2; ++pr)
#pragma unroll
        for (int pb = 0; pb < 2; ++pb)
#pragma unroll
            for (int ct = 0; ct < 4; ++ct)
                acc[pr][pb][ct] = (float4v){0.f, 0.f, 0.f, 0.f};

    const int cbase = wv * 32 + lr;
#pragma unroll
    for (int kk = 0; kk < 13; ++kk) {
        int s = kk * 4 + lq;
        if (s > 48) s = 48;              // padded slots: weights are zero
        const int dh = s / 7, dwd = s % 7;
        short8 ah[2][2], al[2][2];
#pragma unroll
        for (int pr = 0; pr < 2; ++pr)
#pragma unroll
            for (int pb = 0; pb < 2; ++pb) {
                const int off = ((pr + dh) * 134 + cbase + pb * 16 + dwd) * 16;
                ah[pr][pb] = *(const short8*)(p_lds + off);
                al[pr][pb] = *(const short8*)(p_lds + 17152 + off);
            }
#pragma unroll
        for (int ct = 0; ct < 4; ++ct) {
            const short8 bh = *(const short8*)(whi + ((size_t)(kk * 4 + ct) * 64 + l) * 8);
            const short8 bl = *(const short8*)(wlo + ((size_t)(kk * 4 + ct) * 64 + l) * 8);
#pragma unroll
            for (int pr = 0; pr < 2; ++pr)
#pragma unroll
                for (int pb = 0; pb < 2; ++pb) {
                    acc[pr][pb][ct] = __builtin_amdgcn_mfma_f32_16x16x32_bf16(ah[pr][pb], bh, acc[pr][pb][ct], 0, 0, 0);
                    acc[pr][pb][ct] = __builtin_amdgcn_mfma_f32_16x16x32_bf16(al[pr][pb], bh, acc[pr][pb][ct], 0, 0, 0);
                    acc[pr][pb][ct] = __builtin_amdgcn_mfma_f32_16x16x32_bf16(ah[pr][pb], bl, acc[pr][pb][ct], 0, 0, 0);
                }
        }
    }

#pragma unroll
    for (int pr = 0; pr < 2; ++pr) {
        const int h = h0 + pr;
#pragma unroll
        for (int pb = 0; pb < 2; ++pb) {
            const int col0 = w0 + wv * 32 + pb * 16 + lq * 4;
#pragma unroll
            for (int ct = 0; ct < 4; ++ct) {
                const int half = ct >> 1, colocal = (ct & 1) * 16 + lr;
#pragma unroll
                for (int rg = 0; rg < 4; ++rg) {
                    const size_t o = ((((size_t)(b * 2 + half) * 512 + h) * 512) + (col0 + rg)) * 32 + colocal;
                    out[o] = f2bf(fmaxf(acc[pr][pb][ct][rg], 0.f));
                }
            }
        }
    }
}

// ---------------- conv3 weight repack for 32x32x16 path: fold BN scale, fragment-linear ----------------
// layout: [conv][ch][hf][t=s*2+kq][lane][j]   (B-operand: co=ch*32+(l&31), k=(l>>5)*8+j)
__global__ __launch_bounds__(256)
void repack3n_k(const float* __restrict__ w1, const float* __restrict__ w2,
                const float* __restrict__ g1, const float* __restrict__ v1,
                const float* __restrict__ g2, const float* __restrict__ v2,
                unsigned short* __restrict__ dst)
{
    const int conv = blockIdx.z;
    const float* src = (conv < 4) ? (w1 + (size_t)conv * 36864) : (w2 + (size_t)(conv - 4) * 36864);
    const float* g = (conv < 4) ? (g1 + conv * 64) : (g2 + (conv - 4) * 64);
    const float* vv = (conv < 4) ? (v1 + conv * 64) : (v2 + (conv - 4) * 64);
    unsigned short* d = dst + (size_t)conv * 36864;

    const int t = blockIdx.x * 256 + threadIdx.x;   // < 36864
    const int j = t & 7, l = (t >> 3) & 63;
    const int q = t >> 9;            // 0..71
    const int tt = q % 18, m = q / 18;
    const int hf = m & 1, ch = m >> 1;
    const int s = tt >> 1, kq = tt & 1;
    const int co = ch * 32 + (l & 31);
    const int ci = hf * 32 + kq * 16 + (l >> 5) * 8 + j;
    const float sc = g[co] * rsqrtf(vv[co] + 1e-5f);
    d[t] = f2bf(src[((size_t)co * 64 + ci) * 9 + s] * sc);
}

// bias table: bias[conv][co] = beta - mean * scale
__global__ __launch_bounds__(256)
void bias8_k(const float* __restrict__ g1, const float* __restrict__ b1,
             const float* __restrict__ m1, const float* __restrict__ v1,
             const float* __restrict__ g2, const float* __restrict__ b2,
             const float* __restrict__ m2, const float* __restrict__ v2,
             float* __restrict__ bias)
{
    const int t = blockIdx.x * 256 + threadIdx.x;   // < 512
    if (t >= 512) return;
    const int conv = t >> 6, co = t & 63;
    const float* g = (conv < 4) ? (g1 + conv * 64) : (g2 + (conv - 4) * 64);
    const float* be = (conv < 4) ? (b1 + conv * 64) : (b2 + (conv - 4) * 64);
    const float* mn = (conv < 4) ? (m1 + conv * 64) : (m2 + (conv - 4) * 64);
    const float* vv = (conv < 4) ? (v1 + conv * 64) : (v2 + (conv - 4) * 64);
    const float sc = g[co] * rsqrtf(vv[co] + 1e-5f);
    bias[t] = be[co] - mn[co] * sc;
}

// ---------------- conv 3x3 implicit-GEMM, 32x32x16 MFMA ----------------
// A=pixels(LDS), B=weights(streamed from L2 per slot). Each wave computes BOTH co-halves
// from one A-read (1 ds_read -> 2 MFMA). Both ci-half patches prefetched to regs upfront
// (T14): half-1 HBM latency hides under half-0 compute.
// in/skip/out: split-plane NHWC32 bf16 [b][2][512][512][32]
// block 512 = 8 waves: r = wv>>1 (out row 0..3), tq = wv&1 (px half); tile 4 rows x 128 px
// LDS: [6 rows][4 kgrp (xor px&3)][132 px] granules of 16B = 50.7 KB (per ci-half, reused)
template <bool ADD_>
__global__ __launch_bounds__(512, 2)
void conv3_mfma32(const unsigned short* __restrict__ in,
                  const unsigned short* __restrict__ wrp,
                  const float* __restrict__ bias,
                  const unsigned short* __restrict__ skip,
                  unsigned short* __restrict__ out)
{
    __shared__ char p_lds[50688];

    const int id = blockIdx.x;                      // 1024 blocks
    const int lid = (id & 7) * 128 + (id >> 3);     // XCD chunk swizzle
    const int w0 = (lid & 3) * 128;
    const int h0 = ((lid >> 2) & 127) * 4;
    const int b  = lid >> 9;

    const int tid = threadIdx.x;
    const int wv = tid >> 6, l = tid & 63;
    const int r = wv >> 1, tq = wv & 1;
    const int lo5 = l & 31, hi = l >> 5;

    // ---- prefetch BOTH ci-half patches into registers (max MLP) ----
    int4 pre0[7], pre1[7];
#pragma unroll
    for (int it = 0; it < 7; ++it) {
        const int idx = tid + it * 512;
        int4 v0 = make_int4(0, 0, 0, 0), v1 = v0;
        if (idx < 3120) {
            const int row = idx / 520, rem = idx % 520;
            const int px = rem >> 2, kg = rem & 3;
            const int hh = h0 - 1 + row, wc = w0 - 1 + px;
            if (hh >= 0 && hh < 512 && wc >= 0 && wc < 512) {
                const size_t off = ((size_t)hh * 512 + wc) * 32 + kg * 8;
                v0 = *(const int4*)(in + (size_t)(b * 2 + 0) * HWSZ * 32 + off);
                v1 = *(const int4*)(in + (size_t)(b * 2 + 1) * HWSZ * 32 + off);
            }
        }
        pre0[it] = v0; pre1[it] = v1;
    }

    f32x16 acc[2][2];
#pragma unroll
    for (int ch = 0; ch < 2; ++ch)
#pragma unroll
        for (int t4l = 0; t4l < 2; ++t4l)
#pragma unroll
            for (int e = 0; e < 16; ++e) acc[ch][t4l][e] = 0.f;

    auto lds_write = [&](int4* pre) {
#pragma unroll
        for (int it = 0; it < 7; ++it) {
            const int idx = tid + it * 512;
            if (idx < 3120) {
                const int row = idx / 520, rem = idx % 520;
                const int px = rem >> 2, kg = rem & 3;
                *(int4*)(p_lds + ((size_t)((row * 4 + (kg ^ (px & 3))) * 132 + px)) * 16) = pre[it];
            }
        }
    };

    auto kloop = [&](const int hf) {
#pragma unroll
        for (int s = 0; s < 9; ++s) {
            const int dh = s / 3, dwd = s % 3;
            const int row = r + dh;
            short8 pf[2][2];
#pragma unroll
            for (int kq = 0; kq < 2; ++kq) {
                const int kg = kq * 2 + hi;
#pragma unroll
                for (int t4l = 0; t4l < 2; ++t4l) {
                    const int px = (tq * 2 + t4l) * 32 + dwd + lo5;
                    pf[kq][t4l] = *(const short8*)(p_lds +
                        ((size_t)((row * 4 + (kg ^ (px & 3))) * 132 + px)) * 16);
                }
            }
#pragma unroll
            for (int ch = 0; ch < 2; ++ch) {
#pragma unroll
                for (int kq = 0; kq < 2; ++kq) {
                    const short8 wf = *(const short8*)(wrp +
                        (((size_t)(ch * 2 + hf) * 18 + s * 2 + kq) * 64 + l) * 8);
#pragma unroll
                    for (int t4l = 0; t4l < 2; ++t4l)
                        acc[ch][t4l] = __builtin_amdgcn_mfma_f32_32x32x16_bf16(
                            pf[kq][t4l], wf, acc[ch][t4l], 0, 0, 0);
                }
            }
        }
    };

    lds_write(pre0);
    __syncthreads();
    kloop(0);
    __syncthreads();
    lds_write(pre1);
    __syncthreads();
    kloop(1);

    // ---- epilogue: D col = l&31 = co_local; per instr 32 lanes cover one pixel's 64 B ----
    const int h = h0 + r;
#pragma unroll
    for (int ch = 0; ch < 2; ++ch) {
        const float bvs = bias[ch * 32 + lo5];
        const size_t pbase = ((size_t)(b * 2 + ch) * HWSZ + (size_t)h * 512);
#pragma unroll
        for (int t4l = 0; t4l < 2; ++t4l) {
#pragma unroll
            for (int reg = 0; reg < 16; ++reg) {
                const int pxl = (tq * 2 + t4l) * 32 + (reg & 3) + 8 * (reg >> 2) + 4 * hi;
                const size_t o = (pbase + (w0 + pxl)) * 32 + lo5;
                float v = fmaxf(acc[ch][t4l][reg] + bvs, 0.f);
                if (ADD_) v += bf2f(skip[o]);
                out[o] = f2bf(v);
            }
        }
    }
}

// ---------------- conv_last weight repack (16x16 path, phase-major) ----------------
__global__ __launch_bounds__(256)
void repackL_k(const float* __restrict__ wsrc, unsigned short* __restrict__ d)
{
    const int t = blockIdx.x * 256 + threadIdx.x;   // < 18432
    const int j = t & 7, l = (t >> 3) & 63, ct = (t >> 9) & 1, kks = t >> 10;
    const int hf = kks / 9, s = kks % 9;
    const int co = ct * 16 + (l & 15);
    const int ci = hf * 32 + (l >> 4) * 8 + j;
    d[t] = (co < 30) ? f2bf(wsrc[((size_t)co * 64 + ci) * 9 + s]) : (unsigned short)0;
}

// ---------------- conv_last: 16x16 MFMA ci-split 2-phase ----------------
template <int NCOT, int OC>
__global__ __launch_bounds__(256)
void conv3_last(const unsigned short* __restrict__ in,
                const unsigned short* __restrict__ wrp,
                unsigned short* __restrict__ out)
{
    extern __shared__ char smem[];
    unsigned short* w_lds = (unsigned short*)smem;            // NCOT*9*1024 B per phase
    char* p_lds = smem + NCOT * 9 * 1024;                     // 4 planes x 521 granules x 16 B

    const int id = blockIdx.x;                      // 2048 blocks
    const int lid = (id & 7) * 256 + (id >> 3);
    const int w0 = (lid & 3) * 128;
    const int rest = lid >> 2;
    const int h0 = (rest & 255) * 2;
    const int b  = rest >> 8;

    const int tid = threadIdx.x;
    const int wv = tid >> 6, l = tid & 63, lq = l >> 4, lr = l & 15;
    const int cbase = wv * 32 + lr;

    float4v acc[2][2][NCOT];
#pragma unroll
    for (int pr = 0; pr < 2; ++pr)
#pragma unroll
        for (int pb = 0; pb < 2; ++pb)
#pragma unroll
            for (int ct = 0; ct < NCOT; ++ct)
                acc[pr][pb][ct] = (float4v){0.f, 0.f, 0.f, 0.f};

    for (int ph = 0; ph < 2; ++ph) {
        const int4* wsrc = (const int4*)(wrp + (size_t)ph * 9 * NCOT * 512);
        for (int i = tid; i < NCOT * 9 * 64; i += 256)
            ((int4*)w_lds)[i] = wsrc[i];
        const unsigned short* inp = in + (size_t)(b * 2 + ph) * HWSZ * 32;
        for (int idx = tid; idx < 2080; idx += 256) {
            const int G = idx & 3, c = (idx >> 2) % 130, rr = idx / 520;
            const int hh = h0 - 1 + rr, wc = w0 - 1 + c;
            int4 v = make_int4(0, 0, 0, 0);
            if (hh >= 0 && hh < 512 && wc >= 0 && wc < 512)
                v = *(const int4*)(inp + ((size_t)hh * 512 + wc) * 32 + G * 8);
            *(int4*)(p_lds + ((size_t)(G * 521 + rr * 130 + c)) * 16) = v;
        }
        __syncthreads();

#pragma unroll
        for (int s = 0; s < 9; ++s) {
            const int dh = s / 3, dwd = s % 3;
            short8 a[2][2];
#pragma unroll
            for (int pr = 0; pr < 2; ++pr)
#pragma unroll
                for (int pb = 0; pb < 2; ++pb)
                    a[pr][pb] = *(const short8*)(p_lds +
                        ((size_t)(lq * 521 + (pr + dh) * 130 + cbase + pb * 16 + dwd)) * 16);
#pragma unroll
            for (int ct = 0; ct < NCOT; ++ct) {
                const short8 bw = *(const short8*)(w_lds + ((size_t)(s * NCOT + ct) * 64 + l) * 8);
#pragma unroll
                for (int pr = 0; pr < 2; ++pr)
#pragma unroll
                    for (int pb = 0; pb < 2; ++pb)
                        acc[pr][pb][ct] = __builtin_amdgcn_mfma_f32_16x16x32_bf16(
                            a[pr][pb], bw, acc[pr][pb][ct], 0, 0, 0);
            }
        }
        __syncthreads();
    }

#pragma unroll
    for (int pr = 0; pr < 2; ++pr) {
        const int h = h0 + pr;
#pragma unroll
        for (int pb = 0; pb < 2; ++pb) {
            const int col0 = w0 + wv * 32 + pb * 16 + lq * 4;
#pragma unroll
            for (int ct = 0; ct < NCOT; ++ct) {
                const int co = ct * 16 + lr;
                if (co < OC) {
#pragma unroll
                    for (int rg = 0; rg < 4; ++rg) {
                        const size_t o = (((size_t)(b * OC + co) * 512 + h) * 512) + (col0 + rg);
                        out[o] = f2bf(acc[pr][pb][ct][rg]);
                    }
                }
            }
        }
    }
}

// ---------------- fused adaptive filter ----------------
__global__ __launch_bounds__(256)
void filt_fused_k(const unsigned short* __restrict__ wl, const float* __restrict__ base,
                  float* __restrict__ out)
{
    __shared__ float F[516];

    const int id = blockIdx.x;                      // 3072 blocks
    const int lid = (id & 7) * 384 + (id >> 3);
    const int h = lid & 511;
    const int bc = lid >> 9;
    const int b = bc / 3, c = bc % 3;
    const int t = threadIdx.x;

    if (t < 2) F[t] = 0.f;
    if (t >= 254) F[t + 260] = 0.f;

    const size_t rowoff = (size_t)h * 512;
    const unsigned short* wv_p = wl + ((size_t)(b * 30 + c * 10) * HWSZ) + rowoff;
    const unsigned short* wh_p = wv_p + 5 * HWSZ;
    const float* bp = base + (size_t)bc * HWSZ;

#pragma unroll
    for (int wi = 0; wi < 2; ++wi) {
        const int w = t + wi * 256;
        float v[5]; float mx = -1e30f;
#pragma unroll
        for (int i = 0; i < 5; ++i) { v[i] = bf2f(wv_p[(size_t)i * HWSZ + w]); mx = fmaxf(mx, v[i]); }
        float sm = 0.f;
#pragma unroll
        for (int i = 0; i < 5; ++i) { v[i] = __expf(v[i] - mx); sm += v[i]; }
        const float inv = 1.f / sm;
        float acc = 0.f;
#pragma unroll
        for (int i = 0; i < 5; ++i) {
            const int hh = h + i - 2;
            const float bvv = (hh >= 0 && hh < 512) ? bp[(size_t)hh * 512 + w] : 0.f;
            acc = fmaf(bvv, v[i] * inv, acc);
        }
        F[w + 2] = acc;
    }
    __syncthreads();

#pragma unroll
    for (int wi = 0; wi < 2; ++wi) {
        const int w = t + wi * 256;
        float v[5]; float mx = -1e30f;
#pragma unroll
        for (int i = 0; i < 5; ++i) { v[i] = bf2f(wh_p[(size_t)i * HWSZ + w]); mx = fmaxf(mx, v[i]); }
        float sm = 0.f;
#pragma unroll
        for (int i = 0; i < 5; ++i) { v[i] = __expf(v[i] - mx); sm += v[i]; }
        const float inv = 1.f / sm;
        float acc = 0.f;
#pragma unroll
        for (int i = 0; i < 5; ++i)
            acc = fmaf(F[w + i], v[i] * inv, acc);
        out[(size_t)bc * HWSZ + rowoff + w] = acc;
    }
}

extern "C" void kernel_launch(void* const* d_in, const int* in_sizes, int n_in,
                              void* d_out, int out_size, void* d_ws, size_t ws_size,
                              hipStream_t stream)
{
    const float* fm      = (const float*)d_in[0];
    const float* base    = (const float*)d_in[1];
    const float* w_first = (const float*)d_in[2];
    const float* kb_w1   = (const float*)d_in[3];
    const float* kb_g1   = (const float*)d_in[4];
    const float* kb_b1   = (const float*)d_in[5];
    const float* kb_m1   = (const float*)d_in[6];
    const float* kb_v1   = (const float*)d_in[7];
    const float* kb_w2   = (const float*)d_in[8];
    const float* kb_g2   = (const float*)d_in[9];
    const float* kb_b2   = (const float*)d_in[10];
    const float* kb_m2   = (const float*)d_in[11];
    const float* kb_v2   = (const float*)d_in[12];
    const float* w_last  = (const float*)d_in[13];

    char* ws = (char*)d_ws;
    unsigned short* wrp3n  = (unsigned short*)ws;                 // 8*36864 bf16 = 589824 B
    unsigned short* wrpL   = wrp3n + (size_t)8 * 36864;           // 36864 B
    unsigned short* wrp7hi = wrpL + 18432;                        // 53248 B
    unsigned short* wrp7lo = wrp7hi + 26624;                      // 53248 B
    float*          biasws = (float*)(wrp7lo + 26624);            // 2048 B
    unsigned short* actA = (unsigned short*)(ws + (1 << 20));     // 67 MB each, split-plane NHWC32
    unsigned short* actB = actA + (size_t)2 * HWSZ * 64;
    unsigned short* actC = actB + (size_t)2 * HWSZ * 64;
    unsigned short* in7hi = actB;                                 // dead once conv7 done
    unsigned short* in7lo = actB + (size_t)2 * HWSZ * 8;
    unsigned short* logits = actC;                                // planar30; actC free by then

    hipFuncSetAttribute((const void*)conv3_last<2, 30>,
                        hipFuncAttributeMaxDynamicSharedMemorySize, 51776);
    hipFuncSetAttribute((const void*)conv7_mfma,
                        hipFuncAttributeMaxDynamicSharedMemorySize, 34304);

    dim3 blk(256);

    // weight repacks + input prep
    repack3n_k<<<dim3(144, 1, 8), blk, 0, stream>>>(kb_w1, kb_w2, kb_g1, kb_v1, kb_g2, kb_v2, wrp3n);
    bias8_k<<<dim3(2, 1, 1), blk, 0, stream>>>(kb_g1, kb_b1, kb_m1, kb_v1, kb_g2, kb_b2, kb_m2, kb_v2, biasws);
    repackL_k<<<dim3(72, 1, 1), blk, 0, stream>>>(w_last, wrpL);
    repack7_k<<<dim3(104, 1, 1), blk, 0, stream>>>(w_first, wrp7hi, wrp7lo);
    prep7_k<<<dim3(2048, 1, 1), blk, 0, stream>>>(fm, in7hi, in7lo);

    // conv_first -> actA
    conv7_mfma<<<dim3(2048, 1, 1), blk, 34304, stream>>>(in7hi, in7lo, wrp7hi, wrp7lo, actA);

    // residual blocks (32x32x16, both-ch per wave, reg-prefetched staging)
    unsigned short* cur = actA;
    unsigned short* oth = actC;
    for (int i = 0; i < 4; ++i) {
        conv3_mfma32<false><<<dim3(1024, 1, 1), dim3(512), 0, stream>>>(
            cur, wrp3n + (size_t)i * 36864, biasws + i * 64, nullptr, actB);
        conv3_mfma32<true><<<dim3(1024, 1, 1), dim3(512), 0, stream>>>(
            actB, wrp3n + (size_t)(4 + i) * 36864, biasws + (4 + i) * 64, cur, oth);
        unsigned short* t = cur; cur = oth; oth = t;
    }

    // conv_last: 64 -> 30, planar30 bf16 logits
    conv3_last<2, 30><<<dim3(2048, 1, 1), blk, 51776, stream>>>(cur, wrpL, logits);

    // fused adaptive filtering
    filt_fused_k<<<dim3(3072, 1, 1), blk, 0, stream>>>(logits, base, (float*)d_out);
}

// Round 8
// 688.115 us; speedup vs baseline: 1.7135x; 1.7135x over previous
//
#include <hip/hip_runtime.h>
#include <math.h>

typedef __attribute__((ext_vector_type(8)))  short short8;
typedef __attribute__((ext_vector_type(4)))  float float4v;
typedef __attribute__((ext_vector_type(16))) float f32x16;

__device__ __forceinline__ unsigned short f2bf(float f) {
    union { float f; unsigned u; } x; x.f = f;
    unsigned r = x.u + 0x7FFFu + ((x.u >> 16) & 1u);
    return (unsigned short)(r >> 16);
}
__device__ __forceinline__ float bf2f(unsigned short u) {
    union { unsigned u; float f; } x; x.u = ((unsigned)u) << 16;
    return x.f;
}

#define HWSZ ((size_t)512 * 512)

// ---------------- input prep: NCHW f32 (Cin=6) -> NHWC8 bf16 hi + lo planes ----------------
__global__ __launch_bounds__(256)
void prep7_k(const float* __restrict__ in, unsigned short* __restrict__ hi,
             unsigned short* __restrict__ lo)
{
    const int idx = blockIdx.x * 256 + threadIdx.x;   // < 2*512*512
    const int b = idx >> 18, rem = idx & 262143;
    const int h = rem >> 9, w = rem & 511;
    unsigned short vh[8], vl[8];
#pragma unroll
    for (int c = 0; c < 8; ++c) {
        float x = (c < 6) ? in[((size_t)(b * 6 + c)) * HWSZ + (h << 9) + w] : 0.f;
        unsigned short h16 = f2bf(x);
        vh[c] = h16;
        vl[c] = f2bf(x - bf2f(h16));
    }
    const size_t o = ((size_t)idx) * 8;
    *(uint4*)(hi + o) = *(uint4*)vh;
    *(uint4*)(lo + o) = *(uint4*)vl;
}

// ---------------- conv7 weight repack: (64,6,7,7) f32 -> fragment-linear bf16 hi/lo ----------------
__global__ __launch_bounds__(256)
void repack7_k(const float* __restrict__ wsrc, unsigned short* __restrict__ dhi,
               unsigned short* __restrict__ dlo)
{
    const int t = blockIdx.x * 256 + threadIdx.x;   // < 26624
    if (t >= 26624) return;
    const int j = t & 7, l = (t >> 3) & 63, ct = (t >> 9) & 3, kk = t >> 11;
    const int co = ct * 16 + (l & 15);
    const int s = kk * 4 + (l >> 4);
    float v = 0.f;
    if (s < 49 && j < 6)
        v = wsrc[((size_t)(co * 6 + j) * 7 + s / 7) * 7 + s % 7];
    unsigned short h16 = f2bf(v);
    dhi[t] = h16;
    dlo[t] = f2bf(v - bf2f(h16));
}

// ---------------- conv 7x7 MFMA implicit GEMM, split precision, + ReLU ----------------
// out: split-plane NHWC32 bf16  [b][2][512][512][32]
__global__ __launch_bounds__(256)
void conv7_mfma(const unsigned short* __restrict__ inhi,
                const unsigned short* __restrict__ inlo,
                const unsigned short* __restrict__ whi,
                const unsigned short* __restrict__ wlo,
                unsigned short* __restrict__ out)
{
    extern __shared__ char p_lds[];   // [2 planes][8 rows][134 cols][16B]

    const int id = blockIdx.x;                      // 2048 blocks
    const int lid = (id & 7) * 256 + (id >> 3);     // XCD chunk swizzle
    const int w0 = (lid & 3) * 128;
    const int rest = lid >> 2;
    const int h0 = (rest & 255) * 2;
    const int b  = rest >> 8;

    const int tid = threadIdx.x;
    const int wv = tid >> 6, l = tid & 63, lq = l >> 4, lr = l & 15;

    for (int idx = tid; idx < 2144; idx += 256) {   // 2*8*134
        const int plane = idx >= 1072;
        const int rc = plane ? idx - 1072 : idx;
        const int r = rc / 134, c = rc % 134;
        const int hh = h0 - 3 + r, wc = w0 - 3 + c;
        int4 v = make_int4(0, 0, 0, 0);
        if (hh >= 0 && hh < 512 && wc >= 0 && wc < 512) {
            const unsigned short* src = plane ? inlo : inhi;
            v = *(const int4*)(src + ((((size_t)b * 512 + hh) * 512) + wc) * 8);
        }
        *(int4*)(p_lds + (size_t)idx * 16) = v;
    }
    __syncthreads();

    float4v acc[2][2][4];
#pragma unroll
    for (int pr = 0; pr < 2; ++pr)
#pragma unroll
        for (int pb = 0; pb < 2; ++pb)
#pragma unroll
            for (int ct = 0; ct < 4; ++ct)
                acc[pr][pb][ct] = (float4v){0.f, 0.f, 0.f, 0.f};

    const int cbase = wv * 32 + lr;
#pragma unroll
    for (int kk = 0; kk < 13; ++kk) {
        int s = kk * 4 + lq;
        if (s > 48) s = 48;              // padded slots: weights are zero
        const int dh = s / 7, dwd = s % 7;
        short8 ah[2][2], al[2][2];
#pragma unroll
        for (int pr = 0; pr < 2; ++pr)
#pragma unroll
            for (int pb = 0; pb < 2; ++pb) {
                const int off = ((pr + dh) * 134 + cbase + pb * 16 + dwd) * 16;
                ah[pr][pb] = *(const short8*)(p_lds + off);
                al[pr][pb] = *(const short8*)(p_lds + 17152 + off);
            }
#pragma unroll
        for (int ct = 0; ct < 4; ++ct) {
            const short8 bh = *(const short8*)(whi + ((size_t)(kk * 4 + ct) * 64 + l) * 8);
            const short8 bl = *(const short8*)(wlo + ((size_t)(kk * 4 + ct) * 64 + l) * 8);
#pragma unroll
            for (int pr = 0; pr < 2; ++pr)
#pragma unroll
                for (int pb = 0; pb < 2; ++pb) {
                    acc[pr][pb][ct] = __builtin_amdgcn_mfma_f32_16x16x32_bf16(ah[pr][pb], bh, acc[pr][pb][ct], 0, 0, 0);
                    acc[pr][pb][ct] = __builtin_amdgcn_mfma_f32_16x16x32_bf16(al[pr][pb], bh, acc[pr][pb][ct], 0, 0, 0);
                    acc[pr][pb][ct] = __builtin_amdgcn_mfma_f32_16x16x32_bf16(ah[pr][pb], bl, acc[pr][pb][ct], 0, 0, 0);
                }
        }
    }

#pragma unroll
    for (int pr = 0; pr < 2; ++pr) {
        const int h = h0 + pr;
#pragma unroll
        for (int pb = 0; pb < 2; ++pb) {
            const int col0 = w0 + wv * 32 + pb * 16 + lq * 4;
#pragma unroll
            for (int ct = 0; ct < 4; ++ct) {
                const int half = ct >> 1, colocal = (ct & 1) * 16 + lr;
#pragma unroll
                for (int rg = 0; rg < 4; ++rg) {
                    const size_t o = ((((size_t)(b * 2 + half) * 512 + h) * 512) + (col0 + rg)) * 32 + colocal;
                    out[o] = f2bf(fmaxf(acc[pr][pb][ct][rg], 0.f));
                }
            }
        }
    }
}

// ---------------- conv3 weight repack for 32x32x16 path: fold BN scale, fragment-linear ----------------
// layout: [conv][ch][hf][t=s*2+kq][lane][j]   (B-operand: co=ch*32+(l&31), k=(l>>5)*8+j)
__global__ __launch_bounds__(256)
void repack3n_k(const float* __restrict__ w1, const float* __restrict__ w2,
                const float* __restrict__ g1, const float* __restrict__ v1,
                const float* __restrict__ g2, const float* __restrict__ v2,
                unsigned short* __restrict__ dst)
{
    const int conv = blockIdx.z;
    const float* src = (conv < 4) ? (w1 + (size_t)conv * 36864) : (w2 + (size_t)(conv - 4) * 36864);
    const float* g = (conv < 4) ? (g1 + conv * 64) : (g2 + (conv - 4) * 64);
    const float* vv = (conv < 4) ? (v1 + conv * 64) : (v2 + (conv - 4) * 64);
    unsigned short* d = dst + (size_t)conv * 36864;

    const int t = blockIdx.x * 256 + threadIdx.x;   // < 36864
    const int j = t & 7, l = (t >> 3) & 63;
    const int q = t >> 9;            // 0..71
    const int tt = q % 18, m = q / 18;
    const int hf = m & 1, ch = m >> 1;
    const int s = tt >> 1, kq = tt & 1;
    const int co = ch * 32 + (l & 31);
    const int ci = hf * 32 + kq * 16 + (l >> 5) * 8 + j;
    const float sc = g[co] * rsqrtf(vv[co] + 1e-5f);
    d[t] = f2bf(src[((size_t)co * 64 + ci) * 9 + s] * sc);
}

// bias table: bias[conv][co] = beta - mean * scale
__global__ __launch_bounds__(256)
void bias8_k(const float* __restrict__ g1, const float* __restrict__ b1,
             const float* __restrict__ m1, const float* __restrict__ v1,
             const float* __restrict__ g2, const float* __restrict__ b2,
             const float* __restrict__ m2, const float* __restrict__ v2,
             float* __restrict__ bias)
{
    const int t = blockIdx.x * 256 + threadIdx.x;   // < 512
    if (t >= 512) return;
    const int conv = t >> 6, co = t & 63;
    const float* g = (conv < 4) ? (g1 + conv * 64) : (g2 + (conv - 4) * 64);
    const float* be = (conv < 4) ? (b1 + conv * 64) : (b2 + (conv - 4) * 64);
    const float* mn = (conv < 4) ? (m1 + conv * 64) : (m2 + (conv - 4) * 64);
    const float* vv = (conv < 4) ? (v1 + conv * 64) : (v2 + (conv - 4) * 64);
    const float sc = g[co] * rsqrtf(vv[co] + 1e-5f);
    bias[t] = be[co] - mn[co] * sc;
}

// ---------------- conv 3x3 implicit-GEMM, 32x32x16 MFMA ----------------
// A=pixels(LDS), B=weights(registers, BOTH co-halves resident -> 1 A-read feeds 2 MFMAs).
// Both ci-half patches staged to LDS upfront (101 KB, ONE barrier total).
// block 512 = 8 waves (2/SIMD, VGPR cap 256): r = wv>>1 (out row 0..3), tq = wv&1 (px half)
// tile 4 rows x 128 px; LDS per half: [6 rows][4 kgrp (xor px&3)][132 px] x 16B = 50688 B
template <bool ADD_>
__global__ __launch_bounds__(512)
void conv3_mfma32(const unsigned short* __restrict__ in,
                  const unsigned short* __restrict__ wrp,
                  const float* __restrict__ bias,
                  const unsigned short* __restrict__ skip,
                  unsigned short* __restrict__ out)
{
    extern __shared__ char p_lds[];   // 2 x 50688 B

    const int id = blockIdx.x;                      // 1024 blocks
    const int lid = (id & 7) * 128 + (id >> 3);     // XCD chunk swizzle
    const int w0 = (lid & 3) * 128;
    const int h0 = ((lid >> 2) & 127) * 4;
    const int b  = lid >> 9;

    const int tid = threadIdx.x;
    const int wv = tid >> 6, l = tid & 63;
    const int r = wv >> 1, tq = wv & 1;
    const int lo5 = l & 31, hi = l >> 5;

    // ---- stage BOTH ci-half patches: issue all global loads first (max MLP) ----
    int4 pre[14];
#pragma unroll
    for (int half = 0; half < 2; ++half) {
        const unsigned short* inp = in + (size_t)(b * 2 + half) * HWSZ * 32;
#pragma unroll
        for (int it = 0; it < 7; ++it) {
            const int idx = tid + it * 512;
            int4 v = make_int4(0, 0, 0, 0);
            if (idx < 3120) {
                const int row = idx / 520, rem = idx % 520;
                const int px = rem >> 2, kg = rem & 3;
                const int hh = h0 - 1 + row, wc = w0 - 1 + px;
                if (hh >= 0 && hh < 512 && wc >= 0 && wc < 512)
                    v = *(const int4*)(inp + ((size_t)hh * 512 + wc) * 32 + kg * 8);
            }
            pre[half * 7 + it] = v;
        }
    }
#pragma unroll
    for (int half = 0; half < 2; ++half) {
#pragma unroll
        for (int it = 0; it < 7; ++it) {
            const int idx = tid + it * 512;
            if (idx < 3120) {
                const int row = idx / 520, rem = idx % 520;
                const int px = rem >> 2, kg = rem & 3;
                *(int4*)(p_lds + half * 50688 +
                         ((size_t)((row * 4 + (kg ^ (px & 3))) * 132 + px)) * 16) = pre[half * 7 + it];
            }
        }
    }

    f32x16 acc[2][2];
#pragma unroll
    for (int ch = 0; ch < 2; ++ch)
#pragma unroll
        for (int t4l = 0; t4l < 2; ++t4l)
#pragma unroll
            for (int e = 0; e < 16; ++e) acc[ch][t4l][e] = 0.f;

    __syncthreads();

#pragma unroll
    for (int hf = 0; hf < 2; ++hf) {
        // ---- weights for this ci-half, BOTH co-halves, resident in regs (144 VGPR) ----
        short8 wf0[18], wf1[18];
#pragma unroll
        for (int t = 0; t < 18; ++t) {
            wf0[t] = *(const short8*)(wrp + (((size_t)(0 * 2 + hf) * 18 + t) * 64 + l) * 8);
            wf1[t] = *(const short8*)(wrp + (((size_t)(1 * 2 + hf) * 18 + t) * 64 + l) * 8);
        }
        const char* pl = p_lds + hf * 50688;
#pragma unroll
        for (int s = 0; s < 9; ++s) {
            const int dh = s / 3, dwd = s % 3;
            const int row = r + dh;
#pragma unroll
            for (int kq = 0; kq < 2; ++kq) {
                const int kg = kq * 2 + hi;
#pragma unroll
                for (int t4l = 0; t4l < 2; ++t4l) {
                    const int px = (tq * 2 + t4l) * 32 + dwd + lo5;
                    const short8 pf = *(const short8*)(pl +
                        ((size_t)((row * 4 + (kg ^ (px & 3))) * 132 + px)) * 16);
                    acc[0][t4l] = __builtin_amdgcn_mfma_f32_32x32x16_bf16(
                        pf, wf0[s * 2 + kq], acc[0][t4l], 0, 0, 0);
                    acc[1][t4l] = __builtin_amdgcn_mfma_f32_32x32x16_bf16(
                        pf, wf1[s * 2 + kq], acc[1][t4l], 0, 0, 0);
                }
            }
        }
    }

    // ---- epilogue: D col = l&31 = co_local; per instr 32 lanes cover one pixel's 64 B ----
    const int h = h0 + r;
#pragma unroll
    for (int ch = 0; ch < 2; ++ch) {
        const float bvs = bias[ch * 32 + lo5];
        const size_t pbase = ((size_t)(b * 2 + ch) * HWSZ + (size_t)h * 512);
#pragma unroll
        for (int t4l = 0; t4l < 2; ++t4l) {
#pragma unroll
            for (int reg = 0; reg < 16; ++reg) {
                const int pxl = (tq * 2 + t4l) * 32 + (reg & 3) + 8 * (reg >> 2) + 4 * hi;
                const size_t o = (pbase + (w0 + pxl)) * 32 + lo5;
                float v = fmaxf(acc[ch][t4l][reg] + bvs, 0.f);
                if (ADD_) v += bf2f(skip[o]);
                out[o] = f2bf(v);
            }
        }
    }
}

// ---------------- conv_last weight repack (16x16 path, phase-major) ----------------
__global__ __launch_bounds__(256)
void repackL_k(const float* __restrict__ wsrc, unsigned short* __restrict__ d)
{
    const int t = blockIdx.x * 256 + threadIdx.x;   // < 18432
    const int j = t & 7, l = (t >> 3) & 63, ct = (t >> 9) & 1, kks = t >> 10;
    const int hf = kks / 9, s = kks % 9;
    const int co = ct * 16 + (l & 15);
    const int ci = hf * 32 + (l >> 4) * 8 + j;
    d[t] = (co < 30) ? f2bf(wsrc[((size_t)co * 64 + ci) * 9 + s]) : (unsigned short)0;
}

// ---------------- conv_last: 16x16 MFMA ci-split 2-phase ----------------
template <int NCOT, int OC>
__global__ __launch_bounds__(256)
void conv3_last(const unsigned short* __restrict__ in,
                const unsigned short* __restrict__ wrp,
                unsigned short* __restrict__ out)
{
    extern __shared__ char smem[];
    unsigned short* w_lds = (unsigned short*)smem;            // NCOT*9*1024 B per phase
    char* p_lds = smem + NCOT * 9 * 1024;                     // 4 planes x 521 granules x 16 B

    const int id = blockIdx.x;                      // 2048 blocks
    const int lid = (id & 7) * 256 + (id >> 3);
    const int w0 = (lid & 3) * 128;
    const int rest = lid >> 2;
    const int h0 = (rest & 255) * 2;
    const int b  = rest >> 8;

    const int tid = threadIdx.x;
    const int wv = tid >> 6, l = tid & 63, lq = l >> 4, lr = l & 15;
    const int cbase = wv * 32 + lr;

    float4v acc[2][2][NCOT];
#pragma unroll
    for (int pr = 0; pr < 2; ++pr)
#pragma unroll
        for (int pb = 0; pb < 2; ++pb)
#pragma unroll
            for (int ct = 0; ct < NCOT; ++ct)
                acc[pr][pb][ct] = (float4v){0.f, 0.f, 0.f, 0.f};

    for (int ph = 0; ph < 2; ++ph) {
        const int4* wsrc = (const int4*)(wrp + (size_t)ph * 9 * NCOT * 512);
        for (int i = tid; i < NCOT * 9 * 64; i += 256)
            ((int4*)w_lds)[i] = wsrc[i];
        const unsigned short* inp = in + (size_t)(b * 2 + ph) * HWSZ * 32;
        for (int idx = tid; idx < 2080; idx += 256) {
            const int G = idx & 3, c = (idx >> 2) % 130, rr = idx / 520;
            const int hh = h0 - 1 + rr, wc = w0 - 1 + c;
            int4 v = make_int4(0, 0, 0, 0);
            if (hh >= 0 && hh < 512 && wc >= 0 && wc < 512)
                v = *(const int4*)(inp + ((size_t)hh * 512 + wc) * 32 + G * 8);
            *(int4*)(p_lds + ((size_t)(G * 521 + rr * 130 + c)) * 16) = v;
        }
        __syncthreads();

#pragma unroll
        for (int s = 0; s < 9; ++s) {
            const int dh = s / 3, dwd = s % 3;
            short8 a[2][2];
#pragma unroll
            for (int pr = 0; pr < 2; ++pr)
#pragma unroll
                for (int pb = 0; pb < 2; ++pb)
                    a[pr][pb] = *(const short8*)(p_lds +
                        ((size_t)(lq * 521 + (pr + dh) * 130 + cbase + pb * 16 + dwd)) * 16);
#pragma unroll
            for (int ct = 0; ct < NCOT; ++ct) {
                const short8 bw = *(const short8*)(w_lds + ((size_t)(s * NCOT + ct) * 64 + l) * 8);
#pragma unroll
                for (int pr = 0; pr < 2; ++pr)
#pragma unroll
                    for (int pb = 0; pb < 2; ++pb)
                        acc[pr][pb][ct] = __builtin_amdgcn_mfma_f32_16x16x32_bf16(
                            a[pr][pb], bw, acc[pr][pb][ct], 0, 0, 0);
            }
        }
        __syncthreads();
    }

#pragma unroll
    for (int pr = 0; pr < 2; ++pr) {
        const int h = h0 + pr;
#pragma unroll
        for (int pb = 0; pb < 2; ++pb) {
            const int col0 = w0 + wv * 32 + pb * 16 + lq * 4;
#pragma unroll
            for (int ct = 0; ct < NCOT; ++ct) {
                const int co = ct * 16 + lr;
                if (co < OC) {
#pragma unroll
                    for (int rg = 0; rg < 4; ++rg) {
                        const size_t o = (((size_t)(b * OC + co) * 512 + h) * 512) + (col0 + rg);
                        out[o] = f2bf(acc[pr][pb][ct][rg]);
                    }
                }
            }
        }
    }
}

// ---------------- fused adaptive filter ----------------
__global__ __launch_bounds__(256)
void filt_fused_k(const unsigned short* __restrict__ wl, const float* __restrict__ base,
                  float* __restrict__ out)
{
    __shared__ float F[516];

    const int id = blockIdx.x;                      // 3072 blocks
    const int lid = (id & 7) * 384 + (id >> 3);
    const int h = lid & 511;
    const int bc = lid >> 9;
    const int b = bc / 3, c = bc % 3;
    const int t = threadIdx.x;

    if (t < 2) F[t] = 0.f;
    if (t >= 254) F[t + 260] = 0.f;

    const size_t rowoff = (size_t)h * 512;
    const unsigned short* wv_p = wl + ((size_t)(b * 30 + c * 10) * HWSZ) + rowoff;
    const unsigned short* wh_p = wv_p + 5 * HWSZ;
    const float* bp = base + (size_t)bc * HWSZ;

#pragma unroll
    for (int wi = 0; wi < 2; ++wi) {
        const int w = t + wi * 256;
        float v[5]; float mx = -1e30f;
#pragma unroll
        for (int i = 0; i < 5; ++i) { v[i] = bf2f(wv_p[(size_t)i * HWSZ + w]); mx = fmaxf(mx, v[i]); }
        float sm = 0.f;
#pragma unroll
        for (int i = 0; i < 5; ++i) { v[i] = __expf(v[i] - mx); sm += v[i]; }
        const float inv = 1.f / sm;
        float acc = 0.f;
#pragma unroll
        for (int i = 0; i < 5; ++i) {
            const int hh = h + i - 2;
            const float bvv = (hh >= 0 && hh < 512) ? bp[(size_t)hh * 512 + w] : 0.f;
            acc = fmaf(bvv, v[i] * inv, acc);
        }
        F[w + 2] = acc;
    }
    __syncthreads();

#pragma unroll
    for (int wi = 0; wi < 2; ++wi) {
        const int w = t + wi * 256;
        float v[5]; float mx = -1e30f;
#pragma unroll
        for (int i = 0; i < 5; ++i) { v[i] = bf2f(wh_p[(size_t)i * HWSZ + w]); mx = fmaxf(mx, v[i]); }
        float sm = 0.f;
#pragma unroll
        for (int i = 0; i < 5; ++i) { v[i] = __expf(v[i] - mx); sm += v[i]; }
        const float inv = 1.f / sm;
        float acc = 0.f;
#pragma unroll
        for (int i = 0; i < 5; ++i)
            acc = fmaf(F[w + i], v[i] * inv, acc);
        out[(size_t)bc * HWSZ + rowoff + w] = acc;
    }
}

extern "C" void kernel_launch(void* const* d_in, const int* in_sizes, int n_in,
                              void* d_out, int out_size, void* d_ws, size_t ws_size,
                              hipStream_t stream)
{
    const float* fm      = (const float*)d_in[0];
    const float* base    = (const float*)d_in[1];
    const float* w_first = (const float*)d_in[2];
    const float* kb_w1   = (const float*)d_in[3];
    const float* kb_g1   = (const float*)d_in[4];
    const float* kb_b1   = (const float*)d_in[5];
    const float* kb_m1   = (const float*)d_in[6];
    const float* kb_v1   = (const float*)d_in[7];
    const float* kb_w2   = (const float*)d_in[8];
    const float* kb_g2   = (const float*)d_in[9];
    const float* kb_b2   = (const float*)d_in[10];
    const float* kb_m2   = (const float*)d_in[11];
    const float* kb_v2   = (const float*)d_in[12];
    const float* w_last  = (const float*)d_in[13];

    char* ws = (char*)d_ws;
    unsigned short* wrp3n  = (unsigned short*)ws;                 // 8*36864 bf16 = 589824 B
    unsigned short* wrpL   = wrp3n + (size_t)8 * 36864;           // 36864 B
    unsigned short* wrp7hi = wrpL + 18432;                        // 53248 B
    unsigned short* wrp7lo = wrp7hi + 26624;                      // 53248 B
    float*          biasws = (float*)(wrp7lo + 26624);            // 2048 B
    unsigned short* actA = (unsigned short*)(ws + (1 << 20));     // 67 MB each, split-plane NHWC32
    unsigned short* actB = actA + (size_t)2 * HWSZ * 64;
    unsigned short* actC = actB + (size_t)2 * HWSZ * 64;
    unsigned short* in7hi = actB;                                 // dead once conv7 done
    unsigned short* in7lo = actB + (size_t)2 * HWSZ * 8;
    unsigned short* logits = actC;                                // planar30; actC free by then

    hipFuncSetAttribute((const void*)conv3_mfma32<false>,
                        hipFuncAttributeMaxDynamicSharedMemorySize, 101376);
    hipFuncSetAttribute((const void*)conv3_mfma32<true>,
                        hipFuncAttributeMaxDynamicSharedMemorySize, 101376);
    hipFuncSetAttribute((const void*)conv3_last<2, 30>,
                        hipFuncAttributeMaxDynamicSharedMemorySize, 51776);
    hipFuncSetAttribute((const void*)conv7_mfma,
                        hipFuncAttributeMaxDynamicSharedMemorySize, 34304);

    dim3 blk(256);

    // weight repacks + input prep
    repack3n_k<<<dim3(144, 1, 8), blk, 0, stream>>>(kb_w1, kb_w2, kb_g1, kb_v1, kb_g2, kb_v2, wrp3n);
    bias8_k<<<dim3(2, 1, 1), blk, 0, stream>>>(kb_g1, kb_b1, kb_m1, kb_v1, kb_g2, kb_b2, kb_m2, kb_v2, biasws);
    repackL_k<<<dim3(72, 1, 1), blk, 0, stream>>>(w_last, wrpL);
    repack7_k<<<dim3(104, 1, 1), blk, 0, stream>>>(w_first, wrp7hi, wrp7lo);
    prep7_k<<<dim3(2048, 1, 1), blk, 0, stream>>>(fm, in7hi, in7lo);

    // conv_first -> actA
    conv7_mfma<<<dim3(2048, 1, 1), blk, 34304, stream>>>(in7hi, in7lo, wrp7hi, wrp7lo, actA);

    // residual blocks (32x32x16, both-ch weights in regs, single-barrier blocks)
    unsigned short* cur = actA;
    unsigned short* oth = actC;
    for (int i = 0; i < 4; ++i) {
        conv3_mfma32<false><<<dim3(1024, 1, 1), dim3(512), 101376, stream>>>(
            cur, wrp3n + (size_t)i * 36864, biasws + i * 64, nullptr, actB);
        conv3_mfma32<true><<<dim3(1024, 1, 1), dim3(512), 101376, stream>>>(
            actB, wrp3n + (size_t)(4 + i) * 36864, biasws + (4 + i) * 64, cur, oth);
        unsigned short* t = cur; cur = oth; oth = t;
    }

    // conv_last: 64 -> 30, planar30 bf16 logits
    conv3_last<2, 30><<<dim3(2048, 1, 1), blk, 51776, stream>>>(cur, wrpL, logits);

    // fused adaptive filtering
    filt_fused_k<<<dim3(3072, 1, 1), blk, 0, stream>>>(logits, base, (float*)d_out);
}